// Round 1
// baseline (368.105 us; speedup 1.0000x reference)
//
#include <hip/hip_runtime.h>
#include <hip/hip_bf16.h>

// AVWGCN: B=64, N=8192, Din=Dout=64, D=10, C=4, NPC=2048
// Pass 1: sum_EH[b,d,i] = sum_nodes relu(E[node,d]) * x[b,node,i]*mask  (atomic partial sums in ws)
// Pass 2: per node: W = E@Wp (bf16, LDS, [o][i] layout), Z = x + tE@sum_EH (bf16, LDS),
//         out[b,node,o] = Z @ W + E@bias  via mfma_f32_16x16x32_bf16, f32 accum/stores.

#define BB 64
#define NN 8192
#define DI 64
#define DO 64
#define DD 10
#define CC 4
#define NPC 2048

typedef __bf16 bf16;
typedef __bf16 bf16x8 __attribute__((ext_vector_type(8)));
typedef float f32x4 __attribute__((ext_vector_type(4)));

// ---------------- Kernel 1: sum_EH ----------------
// grid = 64 b * 16 chunks (512 nodes each), block = 256 (4 waves)
__global__ __launch_bounds__(256) void k_sumEH(
    const float* __restrict__ x, const float* __restrict__ emb,
    const float* __restrict__ mask, const int* __restrict__ np,
    float* __restrict__ sEH) {
  const int b = blockIdx.x >> 4;
  const int chunk = blockIdx.x & 15;
  const int lane = threadIdx.x & 63;
  const int w = threadIdx.x >> 6;

  float acc[DD];
#pragma unroll
  for (int d = 0; d < DD; ++d) acc[d] = 0.f;

  const float* xb = x + (size_t)b * NN * DI;
  const float* mb = mask + (size_t)b * NN;

  for (int nn = 0; nn < 128; ++nn) {
    const int pos = chunk * 512 + nn * 4 + w;
    const int node = np[pos];
    const float m = mb[node];
    const float xv = xb[(size_t)node * DI + lane] * m;
    const float2* e2 = (const float2*)(emb + (size_t)node * DD);  // 10 floats, 8B aligned
    float2 e0 = e2[0], e1 = e2[1], e4 = e2[2], e6 = e2[3], e8 = e2[4];
    acc[0] = fmaf(fmaxf(e0.x, 0.f), xv, acc[0]);
    acc[1] = fmaf(fmaxf(e0.y, 0.f), xv, acc[1]);
    acc[2] = fmaf(fmaxf(e1.x, 0.f), xv, acc[2]);
    acc[3] = fmaf(fmaxf(e1.y, 0.f), xv, acc[3]);
    acc[4] = fmaf(fmaxf(e4.x, 0.f), xv, acc[4]);
    acc[5] = fmaf(fmaxf(e4.y, 0.f), xv, acc[5]);
    acc[6] = fmaf(fmaxf(e6.x, 0.f), xv, acc[6]);
    acc[7] = fmaf(fmaxf(e6.y, 0.f), xv, acc[7]);
    acc[8] = fmaf(fmaxf(e8.x, 0.f), xv, acc[8]);
    acc[9] = fmaf(fmaxf(e8.y, 0.f), xv, acc[9]);
  }

  __shared__ float red[4][DD][64];
#pragma unroll
  for (int d = 0; d < DD; ++d) red[w][d][lane] = acc[d];
  __syncthreads();

  for (int t = threadIdx.x; t < DD * 64; t += 256) {
    const int d = t >> 6, i = t & 63;
    const float s = red[0][d][i] + red[1][d][i] + red[2][d][i] + red[3][d][i];
    atomicAdd(sEH + ((size_t)b * DD + d) * 64 + i, s);
  }
}

// ---------------- Kernel 2: main ----------------
// grid = N/4 = 2048 blocks, block = 256 (4 waves). Each block: 4 nodes (same client).
__global__ __launch_bounds__(256) void k_main(
    const float* __restrict__ x, const float* __restrict__ emb,
    const float* __restrict__ mask, const float* __restrict__ wp,
    const float* __restrict__ bp, const int* __restrict__ np,
    const float* __restrict__ sEH, float* __restrict__ out) {
  __shared__ float E_l[4][DD];
  __shared__ float tE_l[4][DD];
  __shared__ float bb_l[4][64];
  __shared__ float mask_l[64][4];
  __shared__ __align__(16) bf16 Wt[4][64][72];   // [g][o][i], pad 64->72 (~2x-min conflicts)
  __shared__ __align__(16) bf16 Zl[16][4][72];   // [b_loc][g][i]

  const int tid = threadIdx.x;
  const int lane = tid & 63;
  const int w = tid >> 6;
  const int p0 = blockIdx.x * 4;      // output position base
  const int c = p0 >> 11;             // client (NPC=2048)

  int node[4];
#pragma unroll
  for (int g = 0; g < 4; ++g) node[g] = np[p0 + g];

  // Phase 0: E / tE / mask staging
  if (tid < 40) {
    const int g = tid / 10, d = tid % 10;
    const float e = emb[(size_t)node[g] * DD + d];
    E_l[g][d] = e;
    tE_l[g][d] = fmaxf(e, 0.f);
  }
  {
    const int b = tid >> 2, g = tid & 3;
    mask_l[b][g] = mask[(size_t)b * NN + node[g]];
  }
  __syncthreads();

  // bias: bb_l[g][o] = sum_d E[g][d]*bp[c,d,o]   (g==w, o==lane)
  {
    float acc = 0.f;
#pragma unroll
    for (int d = 0; d < DD; ++d)
      acc = fmaf(E_l[w][d], bp[((size_t)(c * DD + d)) * DO + lane], acc);
    bb_l[w][lane] = acc;
  }

  // Phase 1: W build. wave w owns i in [w*16, w*16+16), lane = o. Wp read once, 4 nodes share.
  {
    float accW0[16], accW1[16], accW2[16], accW3[16];
#pragma unroll
    for (int p = 0; p < 16; ++p) { accW0[p] = 0.f; accW1[p] = 0.f; accW2[p] = 0.f; accW3[p] = 0.f; }
#pragma unroll
    for (int d = 0; d < DD; ++d) {
      const float e0 = E_l[0][d], e1 = E_l[1][d], e2 = E_l[2][d], e3 = E_l[3][d];
      const float* wrow = wp + ((size_t)(c * DD + d) * DI + w * 16) * DO + lane;
#pragma unroll
      for (int p = 0; p < 16; ++p) {
        const float v = wrow[(size_t)p * DO];
        accW0[p] = fmaf(e0, v, accW0[p]);
        accW1[p] = fmaf(e1, v, accW1[p]);
        accW2[p] = fmaf(e2, v, accW2[p]);
        accW3[p] = fmaf(e3, v, accW3[p]);
      }
    }
    float* accs[4] = {accW0, accW1, accW2, accW3};
#pragma unroll
    for (int g = 0; g < 4; ++g) {
      bf16x8 v0, v1;
#pragma unroll
      for (int p = 0; p < 8; ++p) { v0[p] = (bf16)accs[g][p]; v1[p] = (bf16)accs[g][p + 8]; }
      *(bf16x8*)&Wt[g][lane][w * 16] = v0;
      *(bf16x8*)&Wt[g][lane][w * 16 + 8] = v1;
    }
  }

  // hoist tE into registers (used every chunk)
  float tEr[4][DD];
#pragma unroll
  for (int g = 0; g < 4; ++g)
#pragma unroll
    for (int d = 0; d < DD; ++d) tEr[g][d] = tE_l[g][d];
  __syncthreads();

  // Phase 2: 4 chunks of 16 batch rows
  for (int chunk = 0; chunk < 4; ++chunk) {
    // --- Z build: lane = i, wave w covers b_loc = w*4 .. w*4+3 ---
#pragma unroll
    for (int bb4 = 0; bb4 < 4; ++bb4) {
      const int b_loc = w * 4 + bb4;
      const int b = chunk * 16 + b_loc;
      float z0 = x[((size_t)b * NN + node[0]) * DI + lane] * mask_l[b][0];
      float z1 = x[((size_t)b * NN + node[1]) * DI + lane] * mask_l[b][1];
      float z2 = x[((size_t)b * NN + node[2]) * DI + lane] * mask_l[b][2];
      float z3 = x[((size_t)b * NN + node[3]) * DI + lane] * mask_l[b][3];
      const float* sb = sEH + (size_t)b * DD * 64 + lane;
#pragma unroll
      for (int d = 0; d < DD; ++d) {
        const float s = sb[(size_t)d * 64];
        z0 = fmaf(tEr[0][d], s, z0);
        z1 = fmaf(tEr[1][d], s, z1);
        z2 = fmaf(tEr[2][d], s, z2);
        z3 = fmaf(tEr[3][d], s, z3);
      }
      Zl[b_loc][0][lane] = (bf16)z0;
      Zl[b_loc][1][lane] = (bf16)z1;
      Zl[b_loc][2][lane] = (bf16)z2;
      Zl[b_loc][3][lane] = (bf16)z3;
    }
    __syncthreads();

    // --- matmul: wave w = node g; 16x16x32 MFMA, 1 m-tile x 4 n-tiles x 2 k-tiles ---
    {
      const int g = w;
      const int q = lane >> 4, r16 = lane & 15;
      f32x4 acc[4];
#pragma unroll
      for (int nt = 0; nt < 4; ++nt) {
        const float bv = bb_l[g][nt * 16 + r16];
        acc[nt][0] = bv; acc[nt][1] = bv; acc[nt][2] = bv; acc[nt][3] = bv;
      }
#pragma unroll
      for (int kt = 0; kt < 2; ++kt) {
        const int k0 = kt * 32 + q * 8;  // contiguous-8 per lane
        const bf16x8 a = *(const bf16x8*)&Zl[r16][g][k0];
#pragma unroll
        for (int nt = 0; nt < 4; ++nt) {
          const bf16x8 bf = *(const bf16x8*)&Wt[g][nt * 16 + r16][k0];
          acc[nt] = __builtin_amdgcn_mfma_f32_16x16x32_bf16(a, bf, acc[nt], 0, 0, 0);
        }
      }
      // epilogue: D row = 4q+r (b_loc), col = r16 (o within n-tile)
      const size_t pg = (size_t)(p0 + g);
#pragma unroll
      for (int nt = 0; nt < 4; ++nt) {
#pragma unroll
        for (int r = 0; r < 4; ++r) {
          const int bg = chunk * 16 + q * 4 + r;
          out[((size_t)bg * NN + pg) * DO + nt * 16 + r16] = acc[nt][r];
        }
      }
    }
    __syncthreads();
  }
}

extern "C" void kernel_launch(void* const* d_in, const int* in_sizes, int n_in,
                              void* d_out, int out_size, void* d_ws, size_t ws_size,
                              hipStream_t stream) {
  const float* x    = (const float*)d_in[0];
  const float* emb  = (const float*)d_in[1];
  // d_in[2] = poly_coefficients (unused in sprtrelu mode)
  const float* mask = (const float*)d_in[3];
  const float* wp   = (const float*)d_in[4];
  const float* bp   = (const float*)d_in[5];
  const int*   np   = (const int*)d_in[6];
  float* out = (float*)d_out;
  float* sEH = (float*)d_ws;  // [64][10][64] f32 = 160 KB

  hipMemsetAsync(sEH, 0, (size_t)BB * DD * 64 * sizeof(float), stream);
  k_sumEH<<<dim3(BB * 16), dim3(256), 0, stream>>>(x, emb, mask, np, sEH);
  k_main<<<dim3(NN / 4), dim3(256), 0, stream>>>(x, emb, mask, wp, bp, np, sEH, out);
}